// Round 3
// baseline (1520.039 us; speedup 1.0000x reference)
//
#include <hip/hip_runtime.h>
#include <hip/hip_bf16.h>
#include <math.h>

#define HW    16384
#define Bsz   4
#define CIN   32
#define COUT  64
#define RED   16
#define KKN   49
#define GG    4
#define NSPAN 196   // KKN*GG

typedef __hip_bfloat16 bf16;

__device__ __forceinline__ float bf2f(bf16 v) { return __bfloat162float(v); }
__device__ __forceinline__ float gelu_f(float x) {
    return 0.5f * x * (1.0f + erff(x * 0.70710678118654752f));
}

// K1: x1 = gelu(conv1x1(x, w1))  -> x1b (bf16, channel-planar)
//     r  = relu(bn(conv1x1(x1, wr))) -> rbuf (fp32, channel-planar)
__global__ __launch_bounds__(256) void k1_conv1_gelu_reduce(
    const float* __restrict__ x, const float* __restrict__ w1,
    const float* __restrict__ wr, const float* __restrict__ gr,
    const float* __restrict__ br, const float* __restrict__ mr,
    const float* __restrict__ vr,
    bf16* __restrict__ x1b, float* __restrict__ rbuf)
{
    __shared__ float w1s[COUT * CIN];   // 2048
    __shared__ float wrs[RED * COUT];   // 1024
    __shared__ float rsc[RED], rsh[RED];
    for (int i = threadIdx.x; i < COUT * CIN; i += 256) w1s[i] = w1[i];
    for (int i = threadIdx.x; i < RED * COUT; i += 256) wrs[i] = wr[i];
    if (threadIdx.x < RED) {
        int j = threadIdx.x;
        float sc = gr[j] * rsqrtf(vr[j] + 1e-5f);
        rsc[j] = sc;
        rsh[j] = br[j] - mr[j] * sc;
    }
    __syncthreads();

    int tid = blockIdx.x * 256 + threadIdx.x;   // [0, B*HW)
    int b = tid >> 14, p = tid & (HW - 1);

    float xv[CIN];
#pragma unroll
    for (int c = 0; c < CIN; ++c) xv[c] = x[(b * CIN + c) * HW + p];

    float acc[COUT];
#pragma unroll
    for (int o = 0; o < COUT; ++o) acc[o] = 0.f;
#pragma unroll
    for (int c = 0; c < CIN; ++c) {
        float xc = xv[c];
#pragma unroll
        for (int o = 0; o < COUT; ++o) acc[o] += xc * w1s[o * CIN + c];
    }
#pragma unroll
    for (int o = 0; o < COUT; ++o) {
        acc[o] = gelu_f(acc[o]);                         // x1 (fp32)
        x1b[(b * COUT + o) * HW + p] = __float2bfloat16(acc[o]);
    }

    // reduce branch from fp32 x1
#pragma unroll
    for (int j = 0; j < RED; ++j) {
        float s = 0.f;
#pragma unroll
        for (int o = 0; o < COUT; ++o) s += acc[o] * wrs[j * COUT + o];
        s = fmaxf(rsc[j] * s + rsh[j], 0.f);
        rbuf[(b * RED + j) * HW + p] = s;
    }
}

// K3: per (pixel, group) thread: generate 49 dyn weights from r, apply
// involution over 16 group channels, BN1 + GELU -> x2b (bf16).
__global__ __launch_bounds__(256) void k3_involution(
    const bf16* __restrict__ x1b, const float* __restrict__ rbuf,
    const float* __restrict__ wsp, const float* __restrict__ bsp,
    const float* __restrict__ g1, const float* __restrict__ b1,
    const float* __restrict__ m1, const float* __restrict__ v1,
    bf16* __restrict__ x2b)
{
    int tau = blockIdx.x * 256 + threadIdx.x;  // ((b*4+g)*HW + p)
    int p = tau & (HW - 1);
    int bg = tau >> 14;
    int g = bg & 3, b = bg >> 2;
    int h = p >> 7, w = p & 127;

    // whole block shares (b, g): stage this group's span weights
    __shared__ float wssl[KKN * RED];   // 784
    __shared__ float bssl[KKN];
    __shared__ float sc1[RED], sh1[RED];
    int base = g * KKN;                 // span rows [base, base+49)
    for (int i = threadIdx.x; i < KKN * RED; i += 256)
        wssl[i] = wsp[base * RED + i];
    if (threadIdx.x < KKN) bssl[threadIdx.x] = bsp[base + threadIdx.x];
    if (threadIdx.x < RED) {
        int c = threadIdx.x, ch = g * RED + c;
        float sc = g1[ch] * rsqrtf(v1[ch] + 1e-5f);
        sc1[c] = sc;
        sh1[c] = b1[ch] - m1[ch] * sc;
    }
    __syncthreads();

    float r[RED];
#pragma unroll
    for (int j = 0; j < RED; ++j) r[j] = rbuf[(b * RED + j) * HW + p];

    float wk[KKN];
#pragma unroll
    for (int k = 0; k < KKN; ++k) {
        float s = bssl[k];
#pragma unroll
        for (int j = 0; j < RED; ++j) s += r[j] * wssl[k * RED + j];
        wk[k] = s;
    }

    const bf16* xg = x1b + (size_t)(b * COUT + g * RED) * HW;
    float acc[RED];
#pragma unroll 4
    for (int c = 0; c < RED; ++c) {
        const bf16* xc = xg + (size_t)c * HW;
        float a = 0.f;
#pragma unroll
        for (int i = 0; i < 7; ++i) {
            int hh = h + i - 3;
            if (hh < 0 || hh >= 128) continue;
#pragma unroll
            for (int j = 0; j < 7; ++j) {
                int ww = w + j - 3;
                if (ww < 0 || ww >= 128) continue;
                a += wk[i * 7 + j] * bf2f(xc[hh * 128 + ww]);
            }
        }
        acc[c] = a;
    }

#pragma unroll
    for (int c = 0; c < RED; ++c) {
        int ch = g * RED + c;
        x2b[(b * COUT + ch) * HW + p] =
            __float2bfloat16(gelu_f(sc1[c] * acc[c] + sh1[c]));
    }
}

// K4: out = gelu( bn2(conv1x1(x2, w2)) + bnm(conv1x1(x, wm) + bmap) )
__global__ __launch_bounds__(256) void k4_final(
    const bf16* __restrict__ x2b, const float* __restrict__ x,
    const float* __restrict__ w2, const float* __restrict__ g2,
    const float* __restrict__ b2, const float* __restrict__ m2,
    const float* __restrict__ v2,
    const float* __restrict__ wm, const float* __restrict__ bmap,
    const float* __restrict__ gm, const float* __restrict__ betam,
    const float* __restrict__ mm, const float* __restrict__ vm,
    float* __restrict__ out)
{
    __shared__ float w2s[COUT * COUT];   // 4096
    __shared__ float wms[COUT * CIN];    // 2048 (pre-scaled by scm)
    __shared__ float sc2[COUT], shc[COUT], scm[COUT];
    if (threadIdx.x < COUT) {
        int o = threadIdx.x;
        float s2 = g2[o] * rsqrtf(v2[o] + 1e-5f);
        float sm = gm[o] * rsqrtf(vm[o] + 1e-5f);
        sc2[o] = s2;
        scm[o] = sm;
        shc[o] = (b2[o] - m2[o] * s2)
               + (betam[o] - mm[o] * sm + bmap[o] * sm);
    }
    __syncthreads();
    for (int i = threadIdx.x; i < COUT * COUT; i += 256) w2s[i] = w2[i];
    for (int i = threadIdx.x; i < COUT * CIN; i += 256)
        wms[i] = wm[i] * scm[i / CIN];
    __syncthreads();

    int tid = blockIdx.x * 256 + threadIdx.x;   // [0, B*HW)
    int b = tid >> 14, p = tid & (HW - 1);

    float acc[COUT];
#pragma unroll
    for (int o = 0; o < COUT; ++o) acc[o] = 0.f;
#pragma unroll
    for (int c = 0; c < COUT; ++c) {
        float xc = bf2f(x2b[(b * COUT + c) * HW + p]);
#pragma unroll
        for (int o = 0; o < COUT; ++o) acc[o] += xc * w2s[o * COUT + c];
    }
#pragma unroll
    for (int o = 0; o < COUT; ++o) acc[o] = sc2[o] * acc[o] + shc[o];

#pragma unroll
    for (int c = 0; c < CIN; ++c) {
        float xc = x[(b * CIN + c) * HW + p];
#pragma unroll
        for (int o = 0; o < COUT; ++o) acc[o] += xc * wms[o * CIN + c];
    }
#pragma unroll
    for (int o = 0; o < COUT; ++o)
        out[(b * COUT + o) * HW + p] = gelu_f(acc[o]);
}

extern "C" void kernel_launch(void* const* d_in, const int* in_sizes, int n_in,
                              void* d_out, int out_size, void* d_ws, size_t ws_size,
                              hipStream_t stream) {
    const float* x    = (const float*)d_in[0];
    const float* w1   = (const float*)d_in[1];
    const float* wr   = (const float*)d_in[2];
    const float* gr   = (const float*)d_in[3];
    const float* br   = (const float*)d_in[4];
    const float* mr   = (const float*)d_in[5];
    const float* vr   = (const float*)d_in[6];
    const float* wsp  = (const float*)d_in[7];
    const float* bsp  = (const float*)d_in[8];
    const float* g1   = (const float*)d_in[9];
    const float* b1   = (const float*)d_in[10];
    const float* m1   = (const float*)d_in[11];
    const float* v1   = (const float*)d_in[12];
    const float* w2   = (const float*)d_in[13];
    const float* g2   = (const float*)d_in[14];
    const float* b2   = (const float*)d_in[15];
    const float* m2   = (const float*)d_in[16];
    const float* v2   = (const float*)d_in[17];
    const float* wm   = (const float*)d_in[18];
    const float* bmap = (const float*)d_in[19];
    const float* gm   = (const float*)d_in[20];
    const float* betam= (const float*)d_in[21];
    const float* mm   = (const float*)d_in[22];
    const float* vm   = (const float*)d_in[23];

    // workspace layout (20 MB total):
    //   x1b  bf16  B*64*HW  = 4,194,304 el ->  8,388,608 B @ 0
    //   rbuf f32   B*16*HW  = 1,048,576 el ->  4,194,304 B @ 8,388,608
    //   x2b  bf16  B*64*HW  = 4,194,304 el ->  8,388,608 B @ 12,582,912
    bf16*  x1b  = (bf16*)d_ws;
    float* rbuf = (float*)((char*)d_ws + 8388608);
    bf16*  x2b  = (bf16*)((char*)d_ws + 12582912);

    k1_conv1_gelu_reduce<<<Bsz * HW / 256, 256, 0, stream>>>(
        x, w1, wr, gr, br, mr, vr, x1b, rbuf);
    k3_involution<<<Bsz * GG * HW / 256, 256, 0, stream>>>(
        x1b, rbuf, wsp, bsp, g1, b1, m1, v1, x2b);
    k4_final<<<Bsz * HW / 256, 256, 0, stream>>>(
        x2b, x, w2, g2, b2, m2, v2, wm, bmap, gm, betam, mm, vm,
        (float*)d_out);
}

// Round 4
// 294.778 us; speedup vs baseline: 5.1566x; 5.1566x over previous
//
#include <hip/hip_runtime.h>
#include <hip/hip_bf16.h>
#include <math.h>

#define HW    16384
#define Bsz   4
#define CIN   32
#define COUT  64
#define RED   16
#define KKN   49
#define GG    4

typedef __hip_bfloat16 bf16;

__device__ __forceinline__ float bf2f(bf16 v) { return __bfloat162float(v); }
__device__ __forceinline__ float gelu_f(float x) {
    return 0.5f * x * (1.0f + erff(x * 0.70710678118654752f));
}

// K1: x1 = gelu(conv1x1(x, w1)) -> x1b (bf16); r = relu(bn(conv1x1(x1, wr))) -> rbuf
// Block = 64 pixels x 4 chunks. Weights via wave-uniform global (s_load).
__global__ __launch_bounds__(256) void k1_conv1_gelu_reduce(
    const float* __restrict__ x, const float* __restrict__ w1,
    const float* __restrict__ wr, const float* __restrict__ gr,
    const float* __restrict__ br, const float* __restrict__ mr,
    const float* __restrict__ vr,
    bf16* __restrict__ x1b, float* __restrict__ rbuf)
{
    __shared__ float g_lds[COUT][65];   // 64x65 fp32, +1 pad

    int lane  = threadIdx.x & 63;
    int chunk = __builtin_amdgcn_readfirstlane(threadIdx.x >> 6);  // 0..3
    int b  = blockIdx.x >> 8;                  // 256 blocks per batch
    int p  = ((blockIdx.x & 255) << 6) + lane; // 64 pixels per block

    float acc[16];
#pragma unroll
    for (int o = 0; o < 16; ++o) acc[o] = 0.f;
#pragma unroll 4
    for (int c = 0; c < CIN; ++c) {
        float xc = x[(b * CIN + c) * HW + p];
#pragma unroll
        for (int o = 0; o < 16; ++o)
            acc[o] += xc * w1[(chunk * 16 + o) * CIN + c];
    }
#pragma unroll
    for (int o = 0; o < 16; ++o) {
        float gv = gelu_f(acc[o]);
        x1b[(b * COUT + chunk * 16 + o) * HW + p] = __float2bfloat16(gv);
        g_lds[chunk * 16 + o][lane] = gv;
    }
    __syncthreads();

    // r: this thread handles j = chunk*4 .. chunk*4+3 for pixel `lane`
    float racc[4] = {0.f, 0.f, 0.f, 0.f};
#pragma unroll 4
    for (int c = 0; c < COUT; ++c) {
        float gv = g_lds[c][lane];
#pragma unroll
        for (int jj = 0; jj < 4; ++jj)
            racc[jj] += gv * wr[(chunk * 4 + jj) * COUT + c];
    }
#pragma unroll
    for (int jj = 0; jj < 4; ++jj) {
        int j = chunk * 4 + jj;
        float sc = gr[j] * rsqrtf(vr[j] + 1e-5f);
        float sh = br[j] - mr[j] * sc;
        rbuf[(b * RED + j) * HW + p] = fmaxf(sc * racc[jj] + sh, 0.f);
    }
}

// K3: per (pixel, group) thread: 49 dyn weights from r, stream 16 channels
// one scalar accumulator at a time, BN1+GELU -> x2b (bf16).
__global__ __launch_bounds__(256) void k3_involution(
    const bf16* __restrict__ x1b, const float* __restrict__ rbuf,
    const float* __restrict__ wsp, const float* __restrict__ bsp,
    const float* __restrict__ g1, const float* __restrict__ b1,
    const float* __restrict__ m1, const float* __restrict__ v1,
    bf16* __restrict__ x2b)
{
    int bg = blockIdx.x >> 6;           // 64 blocks per (b,g)
    int g = bg & 3, b = bg >> 2;
    int p = ((blockIdx.x & 63) << 8) + threadIdx.x;
    int h = p >> 7, w = p & 127;
    int base = g * KKN;

    float r[RED];
#pragma unroll
    for (int j = 0; j < RED; ++j) r[j] = rbuf[(b * RED + j) * HW + p];

    float wk[KKN];
#pragma unroll
    for (int k = 0; k < KKN; ++k) {
        float s = bsp[base + k];
#pragma unroll
        for (int j = 0; j < RED; ++j) s += r[j] * wsp[(base + k) * RED + j];
        wk[k] = s;
    }

    const bf16* xg = x1b + (size_t)(b * COUT + g * RED) * HW;
    for (int c = 0; c < RED; ++c) {     // not unrolled: keep regs low
        const bf16* xc = xg + (size_t)c * HW;
        float a = 0.f;
#pragma unroll
        for (int i = 0; i < 7; ++i) {
            int hh = h + i - 3;
            if ((unsigned)hh < 128u) {
#pragma unroll
                for (int jx = 0; jx < 7; ++jx) {
                    int ww = w + jx - 3;
                    if ((unsigned)ww < 128u)
                        a += wk[i * 7 + jx] * bf2f(xc[hh * 128 + ww]);
                }
            }
        }
        int ch = g * RED + c;
        float sc = g1[ch] * rsqrtf(v1[ch] + 1e-5f);
        float sh = b1[ch] - m1[ch] * sc;
        x2b[(b * COUT + ch) * HW + p] = __float2bfloat16(gelu_f(sc * a + sh));
    }
}

// K4: out = gelu( bn2(conv1x1(x2,w2)) + bnm(conv1x1(x,wm)+bmap) )
// Block = 64 pixels x 4 chunks of 16 output channels.
__global__ __launch_bounds__(256) void k4_final(
    const bf16* __restrict__ x2b, const float* __restrict__ x,
    const float* __restrict__ w2, const float* __restrict__ g2,
    const float* __restrict__ b2, const float* __restrict__ m2,
    const float* __restrict__ v2,
    const float* __restrict__ wm, const float* __restrict__ bmap,
    const float* __restrict__ gm, const float* __restrict__ betam,
    const float* __restrict__ mm, const float* __restrict__ vm,
    float* __restrict__ out)
{
    int lane  = threadIdx.x & 63;
    int chunk = __builtin_amdgcn_readfirstlane(threadIdx.x >> 6);
    int b = blockIdx.x >> 8;
    int p = ((blockIdx.x & 255) << 6) + lane;

    float acc[16], acm[16];
#pragma unroll
    for (int o = 0; o < 16; ++o) { acc[o] = 0.f; acm[o] = 0.f; }

#pragma unroll 4
    for (int c = 0; c < COUT; ++c) {
        float xc = bf2f(x2b[(b * COUT + c) * HW + p]);
#pragma unroll
        for (int o = 0; o < 16; ++o)
            acc[o] += xc * w2[(chunk * 16 + o) * COUT + c];
    }
#pragma unroll 4
    for (int c = 0; c < CIN; ++c) {
        float xc = x[(b * CIN + c) * HW + p];
#pragma unroll
        for (int o = 0; o < 16; ++o)
            acm[o] += xc * wm[(chunk * 16 + o) * CIN + c];
    }

#pragma unroll
    for (int o = 0; o < 16; ++o) {
        int O = chunk * 16 + o;
        float s2 = g2[O] * rsqrtf(v2[O] + 1e-5f);
        float sm = gm[O] * rsqrtf(vm[O] + 1e-5f);
        float v = s2 * acc[o] + (b2[O] - m2[O] * s2)
                + sm * (acm[o] + bmap[O]) + (betam[O] - mm[O] * sm);
        out[(b * COUT + O) * HW + p] = gelu_f(v);
    }
}

extern "C" void kernel_launch(void* const* d_in, const int* in_sizes, int n_in,
                              void* d_out, int out_size, void* d_ws, size_t ws_size,
                              hipStream_t stream) {
    const float* x    = (const float*)d_in[0];
    const float* w1   = (const float*)d_in[1];
    const float* wr   = (const float*)d_in[2];
    const float* gr   = (const float*)d_in[3];
    const float* br   = (const float*)d_in[4];
    const float* mr   = (const float*)d_in[5];
    const float* vr   = (const float*)d_in[6];
    const float* wsp  = (const float*)d_in[7];
    const float* bsp  = (const float*)d_in[8];
    const float* g1   = (const float*)d_in[9];
    const float* b1   = (const float*)d_in[10];
    const float* m1   = (const float*)d_in[11];
    const float* v1   = (const float*)d_in[12];
    const float* w2   = (const float*)d_in[13];
    const float* g2   = (const float*)d_in[14];
    const float* b2   = (const float*)d_in[15];
    const float* m2   = (const float*)d_in[16];
    const float* v2   = (const float*)d_in[17];
    const float* wm   = (const float*)d_in[18];
    const float* bmap = (const float*)d_in[19];
    const float* gm   = (const float*)d_in[20];
    const float* betam= (const float*)d_in[21];
    const float* mm   = (const float*)d_in[22];
    const float* vm   = (const float*)d_in[23];

    // workspace: x1b bf16 (8 MB) | rbuf f32 (4 MB) | x2b bf16 (8 MB)
    bf16*  x1b  = (bf16*)d_ws;
    float* rbuf = (float*)((char*)d_ws + 8388608);
    bf16*  x2b  = (bf16*)((char*)d_ws + 12582912);

    k1_conv1_gelu_reduce<<<Bsz * HW / 64, 256, 0, stream>>>(
        x, w1, wr, gr, br, mr, vr, x1b, rbuf);
    k3_involution<<<Bsz * GG * HW / 256, 256, 0, stream>>>(
        x1b, rbuf, wsp, bsp, g1, b1, m1, v1, x2b);
    k4_final<<<Bsz * HW / 64, 256, 0, stream>>>(
        x2b, x, w2, g2, b2, m2, v2, wm, bmap, gm, betam, mm, vm,
        (float*)d_out);
}

// Round 5
// 207.265 us; speedup vs baseline: 7.3338x; 1.4222x over previous
//
#include <hip/hip_runtime.h>
#include <hip/hip_bf16.h>
#include <math.h>

#define HW    16384
#define Bsz   4
#define CIN   32
#define COUT  64
#define RED   16
#define KKN   49
#define GG    4

typedef __hip_bfloat16 bf16;

__device__ __forceinline__ float bf2f(bf16 v) { return __bfloat162float(v); }
__device__ __forceinline__ float gelu_f(float x) {
    return 0.5f * x * (1.0f + erff(x * 0.70710678118654752f));
}

// K1: x1 = gelu(conv1x1(x, w1)) -> x1b (bf16); r = relu(bn(conv1x1(x1, wr))) -> rbuf
__global__ __launch_bounds__(256, 4) void k1_conv1_gelu_reduce(
    const float* __restrict__ x, const float* __restrict__ w1,
    const float* __restrict__ wr, const float* __restrict__ gr,
    const float* __restrict__ br, const float* __restrict__ mr,
    const float* __restrict__ vr,
    bf16* __restrict__ x1b, float* __restrict__ rbuf)
{
    __shared__ float g_lds[COUT][65];

    int lane  = threadIdx.x & 63;
    int chunk = __builtin_amdgcn_readfirstlane(threadIdx.x >> 6);  // 0..3
    int b  = blockIdx.x >> 8;
    int p  = ((blockIdx.x & 255) << 6) + lane;

    float acc[16];
#pragma unroll
    for (int o = 0; o < 16; ++o) acc[o] = 0.f;
#pragma unroll 8
    for (int c = 0; c < CIN; ++c) {
        float xc = x[(b * CIN + c) * HW + p];
#pragma unroll
        for (int o = 0; o < 16; ++o)
            acc[o] += xc * w1[(chunk * 16 + o) * CIN + c];
    }
#pragma unroll
    for (int o = 0; o < 16; ++o) {
        float gv = gelu_f(acc[o]);
        x1b[(b * COUT + chunk * 16 + o) * HW + p] = __float2bfloat16(gv);
        g_lds[chunk * 16 + o][lane] = gv;
    }
    __syncthreads();

    float racc[4] = {0.f, 0.f, 0.f, 0.f};
#pragma unroll 8
    for (int c = 0; c < COUT; ++c) {
        float gv = g_lds[c][lane];
#pragma unroll
        for (int jj = 0; jj < 4; ++jj)
            racc[jj] += gv * wr[(chunk * 4 + jj) * COUT + c];
    }
#pragma unroll
    for (int jj = 0; jj < 4; ++jj) {
        int j = chunk * 4 + jj;
        float sc = gr[j] * rsqrtf(vr[j] + 1e-5f);
        float sh = br[j] - mr[j] * sc;
        rbuf[(b * RED + j) * HW + p] = fmaxf(sc * racc[jj] + sh, 0.f);
    }
}

// K2: wk = ws . r + bs  per pixel, per group -> wbuf bf16 [B, G, 49, HW]
// ws weights via wave-uniform s_load (SGPR operand on the FMA).
__global__ __launch_bounds__(256, 4) void k2_genw(
    const float* __restrict__ rbuf, const float* __restrict__ wsp,
    const float* __restrict__ bsp, bf16* __restrict__ wbuf)
{
    int blk = blockIdx.x & 63;
    int g   = (blockIdx.x >> 6) & 3;
    int b   = blockIdx.x >> 8;
    int p   = (blk << 8) + threadIdx.x;

    float r[RED];
#pragma unroll
    for (int j = 0; j < RED; ++j) r[j] = rbuf[(b * RED + j) * HW + p];

    const float* wrow = wsp + g * KKN * RED;
    const float* brow = bsp + g * KKN;
    bf16* wout = wbuf + ((size_t)(b * GG + g) * KKN) * HW + p;

#pragma unroll 4
    for (int k = 0; k < KKN; ++k) {
        float s = brow[k];
#pragma unroll
        for (int j = 0; j < RED; ++j) s += r[j] * wrow[k * RED + j];
        wout[(size_t)k * HW] = __float2bfloat16(s);
    }
}

// K3: involution apply, tap-outer / 16-channels-inner. BN1+GELU -> x2b.
__global__ __launch_bounds__(256, 4) void k3_involution(
    const bf16* __restrict__ x1b, const bf16* __restrict__ wbuf,
    const float* __restrict__ g1, const float* __restrict__ b1,
    const float* __restrict__ m1, const float* __restrict__ v1,
    bf16* __restrict__ x2b)
{
    int bg = blockIdx.x >> 6;
    int g = bg & 3, b = bg >> 2;
    int p = ((blockIdx.x & 63) << 8) + threadIdx.x;
    int h = p >> 7, w0 = p & 127;

    const bf16* wb = wbuf + ((size_t)(b * GG + g) * KKN) * HW + p;
    const bf16* xg = x1b + (size_t)(b * COUT + g * RED) * HW;

    float acc[RED];
#pragma unroll
    for (int c = 0; c < RED; ++c) acc[c] = 0.f;

#pragma unroll
    for (int i = 0; i < 7; ++i) {
        int hh = h + i - 3;                       // wave-uniform
        if ((unsigned)hh < 128u) {
#pragma unroll
            for (int j = 0; j < 7; ++j) {
                int ww = w0 + j - 3;
                float wv = bf2f(wb[(size_t)(i * 7 + j) * HW]);
                if ((unsigned)ww < 128u) {
                    int off = hh * 128 + ww;
#pragma unroll
                    for (int c = 0; c < RED; ++c)
                        acc[c] += wv * bf2f(xg[(size_t)c * HW + off]);
                }
            }
        }
    }

#pragma unroll
    for (int c = 0; c < RED; ++c) {
        int ch = g * RED + c;
        float sc = g1[ch] * rsqrtf(v1[ch] + 1e-5f);
        float sh = b1[ch] - m1[ch] * sc;
        x2b[(b * COUT + ch) * HW + p] = __float2bfloat16(gelu_f(sc * acc[c] + sh));
    }
}

// K4: out = gelu( bn2(conv1x1(x2,w2)) + bnm(conv1x1(x,wm)+bmap) )
__global__ __launch_bounds__(256, 4) void k4_final(
    const bf16* __restrict__ x2b, const float* __restrict__ x,
    const float* __restrict__ w2, const float* __restrict__ g2,
    const float* __restrict__ b2, const float* __restrict__ m2,
    const float* __restrict__ v2,
    const float* __restrict__ wm, const float* __restrict__ bmap,
    const float* __restrict__ gm, const float* __restrict__ betam,
    const float* __restrict__ mm, const float* __restrict__ vm,
    float* __restrict__ out)
{
    int lane  = threadIdx.x & 63;
    int chunk = __builtin_amdgcn_readfirstlane(threadIdx.x >> 6);
    int b = blockIdx.x >> 8;
    int p = ((blockIdx.x & 255) << 6) + lane;

    float acc[16], acm[16];
#pragma unroll
    for (int o = 0; o < 16; ++o) { acc[o] = 0.f; acm[o] = 0.f; }

#pragma unroll 8
    for (int c = 0; c < COUT; ++c) {
        float xc = bf2f(x2b[(b * COUT + c) * HW + p]);
#pragma unroll
        for (int o = 0; o < 16; ++o)
            acc[o] += xc * w2[(chunk * 16 + o) * COUT + c];
    }
#pragma unroll 8
    for (int c = 0; c < CIN; ++c) {
        float xc = x[(b * CIN + c) * HW + p];
#pragma unroll
        for (int o = 0; o < 16; ++o)
            acm[o] += xc * wm[(chunk * 16 + o) * CIN + c];
    }

#pragma unroll
    for (int o = 0; o < 16; ++o) {
        int O = chunk * 16 + o;
        float s2 = g2[O] * rsqrtf(v2[O] + 1e-5f);
        float sm = gm[O] * rsqrtf(vm[O] + 1e-5f);
        float v = s2 * acc[o] + (b2[O] - m2[O] * s2)
                + sm * (acm[o] + bmap[O]) + (betam[O] - mm[O] * sm);
        out[(b * COUT + O) * HW + p] = gelu_f(v);
    }
}

extern "C" void kernel_launch(void* const* d_in, const int* in_sizes, int n_in,
                              void* d_out, int out_size, void* d_ws, size_t ws_size,
                              hipStream_t stream) {
    const float* x    = (const float*)d_in[0];
    const float* w1   = (const float*)d_in[1];
    const float* wr   = (const float*)d_in[2];
    const float* gr   = (const float*)d_in[3];
    const float* br   = (const float*)d_in[4];
    const float* mr   = (const float*)d_in[5];
    const float* vr   = (const float*)d_in[6];
    const float* wsp  = (const float*)d_in[7];
    const float* bsp  = (const float*)d_in[8];
    const float* g1   = (const float*)d_in[9];
    const float* b1   = (const float*)d_in[10];
    const float* m1   = (const float*)d_in[11];
    const float* v1   = (const float*)d_in[12];
    const float* w2   = (const float*)d_in[13];
    const float* g2   = (const float*)d_in[14];
    const float* b2   = (const float*)d_in[15];
    const float* v2   = (const float*)d_in[17];
    const float* m2   = (const float*)d_in[16];
    const float* wm   = (const float*)d_in[18];
    const float* bmap = (const float*)d_in[19];
    const float* gm   = (const float*)d_in[20];
    const float* betam= (const float*)d_in[21];
    const float* mm   = (const float*)d_in[22];
    const float* vm   = (const float*)d_in[23];

    // workspace:
    //   x1b  bf16  8,388,608 B @ 0
    //   rbuf f32   4,194,304 B @ 8,388,608
    //   wbuf bf16  25,690,112 B @ 12,582,912   [B,G,49,HW]
    //   x2b  bf16  8,388,608 B @ 38,273,024    (total ~46.7 MB)
    bf16*  x1b  = (bf16*)d_ws;
    float* rbuf = (float*)((char*)d_ws + 8388608);
    bf16*  wbuf = (bf16*)((char*)d_ws + 12582912);
    bf16*  x2b  = (bf16*)((char*)d_ws + 38273024);

    k1_conv1_gelu_reduce<<<Bsz * HW / 64, 256, 0, stream>>>(
        x, w1, wr, gr, br, mr, vr, x1b, rbuf);
    k2_genw<<<Bsz * GG * HW / 256, 256, 0, stream>>>(rbuf, wsp, bsp, wbuf);
    k3_involution<<<Bsz * GG * HW / 256, 256, 0, stream>>>(
        x1b, wbuf, g1, b1, m1, v1, x2b);
    k4_final<<<Bsz * HW / 64, 256, 0, stream>>>(
        x2b, x, w2, g2, b2, m2, v2, wm, bmap, gm, betam, mm, vm,
        (float*)d_out);
}

// Round 6
// 205.818 us; speedup vs baseline: 7.3854x; 1.0070x over previous
//
#include <hip/hip_runtime.h>
#include <hip/hip_bf16.h>
#include <math.h>

#define HW    16384
#define Bsz   4
#define CIN   32
#define COUT  64
#define RED   16
#define KKN   49
#define GG    4

typedef __hip_bfloat16 bf16;

__device__ __forceinline__ float bf2f(bf16 v) { return __bfloat162float(v); }
__device__ __forceinline__ float gelu_f(float x) {
    return 0.5f * x * (1.0f + erff(x * 0.70710678118654752f));
}
// unpack a dword holding two bf16 (little-endian: lo = even pixel)
__device__ __forceinline__ void unpack_bf2(unsigned u, float& lo, float& hi) {
    unsigned ulo = u << 16, uhi = u & 0xffff0000u;
    lo = __uint_as_float(ulo);
    hi = __uint_as_float(uhi);
}
__device__ __forceinline__ unsigned pack_bf2(float lo, float hi) {
    unsigned a = __float_as_uint(lo), b = __float_as_uint(hi);
    // round-to-nearest-even bf16
    a += 0x7fff + ((a >> 16) & 1);
    b += 0x7fff + ((b >> 16) & 1);
    return (a >> 16) | (b & 0xffff0000u);
}

// K1: x1 = gelu(conv1x1(x, w1)) -> x1b (bf16); r = relu(bn(conv1x1(x1, wr))) -> rbuf
// Block = 128 px x 4 chunks; 2 px per thread.
__global__ __launch_bounds__(256, 4) void k1_conv1_gelu_reduce(
    const float* __restrict__ x, const float* __restrict__ w1,
    const float* __restrict__ wr, const float* __restrict__ gr,
    const float* __restrict__ br, const float* __restrict__ mr,
    const float* __restrict__ vr,
    bf16* __restrict__ x1b, float* __restrict__ rbuf)
{
    __shared__ float g_lds[COUT][130];

    int lane  = threadIdx.x & 63;
    int chunk = __builtin_amdgcn_readfirstlane(threadIdx.x >> 6);  // 0..3
    int b     = blockIdx.x >> 7;                 // 128 blocks per batch
    int pbase = (blockIdx.x & 127) << 7;         // 128 px per block
    int p0    = pbase + lane * 2;

    float acc[32];
#pragma unroll
    for (int i = 0; i < 32; ++i) acc[i] = 0.f;
#pragma unroll 4
    for (int c = 0; c < CIN; ++c) {
        float2 xc = *(const float2*)&x[(b * CIN + c) * HW + p0];
#pragma unroll
        for (int o = 0; o < 16; ++o) {
            float wv = w1[(chunk * 16 + o) * CIN + c];
            acc[2 * o]     += xc.x * wv;
            acc[2 * o + 1] += xc.y * wv;
        }
    }
#pragma unroll
    for (int o = 0; o < 16; ++o) {
        int O = chunk * 16 + o;
        float g0 = gelu_f(acc[2 * o]);
        float g1 = gelu_f(acc[2 * o + 1]);
        *(unsigned*)&x1b[(b * COUT + O) * HW + p0] = pack_bf2(g0, g1);
        g_lds[O][lane * 2]     = g0;
        g_lds[O][lane * 2 + 1] = g1;
    }
    __syncthreads();

    // reduce branch: this thread covers px (pbase+lane) and (pbase+64+lane)
    float ra[4] = {0.f, 0.f, 0.f, 0.f}, rb[4] = {0.f, 0.f, 0.f, 0.f};
#pragma unroll 4
    for (int c = 0; c < COUT; ++c) {
        float ga = g_lds[c][lane];
        float gb = g_lds[c][64 + lane];
#pragma unroll
        for (int jj = 0; jj < 4; ++jj) {
            float wv = wr[(chunk * 4 + jj) * COUT + c];
            ra[jj] += ga * wv;
            rb[jj] += gb * wv;
        }
    }
#pragma unroll
    for (int jj = 0; jj < 4; ++jj) {
        int j = chunk * 4 + jj;
        float sc = gr[j] * rsqrtf(vr[j] + 1e-5f);
        float sh = br[j] - mr[j] * sc;
        rbuf[(b * RED + j) * HW + pbase + lane]      = fmaxf(sc * ra[jj] + sh, 0.f);
        rbuf[(b * RED + j) * HW + pbase + 64 + lane] = fmaxf(sc * rb[jj] + sh, 0.f);
    }
}

// K23 fused: per (b,g) block of 256 px.
// Phase 1: wk[49] per pixel into LDS. Phase 2: tap-outer involution, BN1+GELU.
__global__ __launch_bounds__(256, 3) void k23_involution(
    const bf16* __restrict__ x1b, const float* __restrict__ rbuf,
    const float* __restrict__ wsp, const float* __restrict__ bsp,
    const float* __restrict__ g1, const float* __restrict__ b1,
    const float* __restrict__ m1, const float* __restrict__ v1,
    bf16* __restrict__ x2b)
{
    __shared__ float wk_lds[256 * KKN];   // 50176 B; stride 49 (17 mod 32) conflict-free

    int bg = blockIdx.x >> 6;
    int g = bg & 3, b = bg >> 2;
    int p = ((blockIdx.x & 63) << 8) + threadIdx.x;
    int h = p >> 7, w0 = p & 127;

    float r[RED];
#pragma unroll
    for (int j = 0; j < RED; ++j) r[j] = rbuf[(b * RED + j) * HW + p];

    const float* wrow = wsp + g * KKN * RED;
    const float* brow = bsp + g * KKN;
#pragma unroll 7
    for (int k = 0; k < KKN; ++k) {
        float s = brow[k];
#pragma unroll
        for (int j = 0; j < RED; ++j) s += r[j] * wrow[k * RED + j];
        wk_lds[threadIdx.x * KKN + k] = s;
    }
    __syncthreads();

    const bf16* xg = x1b + (size_t)(b * COUT + g * RED) * HW;
    float acc[RED];
#pragma unroll
    for (int c = 0; c < RED; ++c) acc[c] = 0.f;

#pragma unroll
    for (int i = 0; i < 7; ++i) {
        int hh = h + i - 3;                       // wave-uniform
        if ((unsigned)hh < 128u) {
#pragma unroll
            for (int j = 0; j < 7; ++j) {
                int ww = w0 + j - 3;
                float wv = wk_lds[threadIdx.x * KKN + i * 7 + j];
                if ((unsigned)ww < 128u) {
                    int off = hh * 128 + ww;
#pragma unroll
                    for (int c = 0; c < RED; ++c)
                        acc[c] += wv * bf2f(xg[(size_t)c * HW + off]);
                }
            }
        }
    }

#pragma unroll
    for (int c = 0; c < RED; ++c) {
        int ch = g * RED + c;
        float sc = g1[ch] * rsqrtf(v1[ch] + 1e-5f);
        float sh = b1[ch] - m1[ch] * sc;
        x2b[(b * COUT + ch) * HW + p] = __float2bfloat16(gelu_f(sc * acc[c] + sh));
    }
}

// K4: out = gelu( bn2(conv1x1(x2,w2)) + bnm(conv1x1(x,wm)+bmap) )
// Block = 128 px x 4 chunks; 2 px per thread; single accumulator set
// via acc' = (sum2)*(s2/sm) + summ; out = sm*acc' + shc.
__global__ __launch_bounds__(256, 4) void k4_final(
    const bf16* __restrict__ x2b, const float* __restrict__ x,
    const float* __restrict__ w2, const float* __restrict__ g2,
    const float* __restrict__ b2, const float* __restrict__ m2,
    const float* __restrict__ v2,
    const float* __restrict__ wm, const float* __restrict__ bmap,
    const float* __restrict__ gm, const float* __restrict__ betam,
    const float* __restrict__ mm, const float* __restrict__ vm,
    float* __restrict__ out)
{
    int lane  = threadIdx.x & 63;
    int chunk = __builtin_amdgcn_readfirstlane(threadIdx.x >> 6);
    int b     = blockIdx.x >> 7;
    int p0    = ((blockIdx.x & 127) << 7) + lane * 2;

    float acc[32];
#pragma unroll
    for (int i = 0; i < 32; ++i) acc[i] = 0.f;

#pragma unroll 4
    for (int c = 0; c < COUT; ++c) {
        unsigned u = *(const unsigned*)&x2b[(b * COUT + c) * HW + p0];
        float xc0, xc1;
        unpack_bf2(u, xc0, xc1);
#pragma unroll
        for (int o = 0; o < 16; ++o) {
            float wv = w2[(chunk * 16 + o) * COUT + c];
            acc[2 * o]     += xc0 * wv;
            acc[2 * o + 1] += xc1 * wv;
        }
    }
    // scale by s2/sm, then accumulate mapping branch
#pragma unroll
    for (int o = 0; o < 16; ++o) {
        int O = chunk * 16 + o;
        float s2 = g2[O] * rsqrtf(v2[O] + 1e-5f);
        float sm = gm[O] * rsqrtf(vm[O] + 1e-5f);
        float ratio = s2 / sm;
        acc[2 * o]     *= ratio;
        acc[2 * o + 1] *= ratio;
    }
#pragma unroll 4
    for (int c = 0; c < CIN; ++c) {
        float2 xc = *(const float2*)&x[(b * CIN + c) * HW + p0];
#pragma unroll
        for (int o = 0; o < 16; ++o) {
            float wv = wm[(chunk * 16 + o) * CIN + c];
            acc[2 * o]     += xc.x * wv;
            acc[2 * o + 1] += xc.y * wv;
        }
    }
#pragma unroll
    for (int o = 0; o < 16; ++o) {
        int O = chunk * 16 + o;
        float s2 = g2[O] * rsqrtf(v2[O] + 1e-5f);
        float sm = gm[O] * rsqrtf(vm[O] + 1e-5f);
        float shc = (b2[O] - m2[O] * s2)
                  + (betam[O] + (bmap[O] - mm[O]) * sm);
        float2 v;
        v.x = gelu_f(sm * acc[2 * o]     + shc);
        v.y = gelu_f(sm * acc[2 * o + 1] + shc);
        *(float2*)&out[(b * COUT + O) * HW + p0] = v;
    }
}

extern "C" void kernel_launch(void* const* d_in, const int* in_sizes, int n_in,
                              void* d_out, int out_size, void* d_ws, size_t ws_size,
                              hipStream_t stream) {
    const float* x    = (const float*)d_in[0];
    const float* w1   = (const float*)d_in[1];
    const float* wr   = (const float*)d_in[2];
    const float* gr   = (const float*)d_in[3];
    const float* br   = (const float*)d_in[4];
    const float* mr   = (const float*)d_in[5];
    const float* vr   = (const float*)d_in[6];
    const float* wsp  = (const float*)d_in[7];
    const float* bsp  = (const float*)d_in[8];
    const float* g1   = (const float*)d_in[9];
    const float* b1   = (const float*)d_in[10];
    const float* m1   = (const float*)d_in[11];
    const float* v1   = (const float*)d_in[12];
    const float* w2   = (const float*)d_in[13];
    const float* g2   = (const float*)d_in[14];
    const float* b2   = (const float*)d_in[15];
    const float* m2   = (const float*)d_in[16];
    const float* v2   = (const float*)d_in[17];
    const float* wm   = (const float*)d_in[18];
    const float* bmap = (const float*)d_in[19];
    const float* gm   = (const float*)d_in[20];
    const float* betam= (const float*)d_in[21];
    const float* mm   = (const float*)d_in[22];
    const float* vm   = (const float*)d_in[23];

    // workspace: x1b bf16 (8 MB) | rbuf f32 (4 MB) | x2b bf16 (8 MB)
    bf16*  x1b  = (bf16*)d_ws;
    float* rbuf = (float*)((char*)d_ws + 8388608);
    bf16*  x2b  = (bf16*)((char*)d_ws + 12582912);

    k1_conv1_gelu_reduce<<<Bsz * HW / 128, 256, 0, stream>>>(
        x, w1, wr, gr, br, mr, vr, x1b, rbuf);
    k23_involution<<<Bsz * GG * HW / 256, 256, 0, stream>>>(
        x1b, rbuf, wsp, bsp, g1, b1, m1, v1, x2b);
    k4_final<<<Bsz * HW / 128, 256, 0, stream>>>(
        x2b, x, w2, g2, b2, m2, v2, wm, bmap, gm, betam, mm, vm,
        (float*)d_out);
}

// Round 7
// 197.144 us; speedup vs baseline: 7.7103x; 1.0440x over previous
//
#include <hip/hip_runtime.h>
#include <hip/hip_bf16.h>
#include <math.h>

#define HW    16384
#define Bsz   4
#define CIN   32
#define COUT  64
#define RED   16
#define KKN   49
#define GG    4

typedef __hip_bfloat16 bf16;

__device__ __forceinline__ float gelu_f(float x) {
    return 0.5f * x * (1.0f + erff(x * 0.70710678118654752f));
}
__device__ __forceinline__ void unpack_bf2(unsigned u, float& lo, float& hi) {
    lo = __uint_as_float(u << 16);
    hi = __uint_as_float(u & 0xffff0000u);
}
__device__ __forceinline__ unsigned pack_bf2(float lo, float hi) {
    unsigned a = __float_as_uint(lo), b = __float_as_uint(hi);
    a += 0x7fff + ((a >> 16) & 1);
    b += 0x7fff + ((b >> 16) & 1);
    return (a >> 16) | (b & 0xffff0000u);
}

// K1: x1 = gelu(conv1x1(x, w1)) -> x1b interleaved [b][g][p][c16] bf16
//     r  = relu(bn(conv1x1(x1, wr))) -> rbuf interleaved [b][p][j16] f32
// Block = 64 px x 4 chunks (chunk == group). Weights via wave-uniform s_load.
__global__ __launch_bounds__(256, 4) void k1_conv1_gelu_reduce(
    const float* __restrict__ x, const float* __restrict__ w1,
    const float* __restrict__ wr, const float* __restrict__ gr,
    const float* __restrict__ br, const float* __restrict__ mr,
    const float* __restrict__ vr,
    unsigned* __restrict__ x1b, float* __restrict__ rbuf)
{
    __shared__ float g_lds[COUT][65];

    int lane  = threadIdx.x & 63;
    int chunk = __builtin_amdgcn_readfirstlane(threadIdx.x >> 6);  // == group
    int b     = blockIdx.x >> 8;
    int p     = ((blockIdx.x & 255) << 6) + lane;

    float xv[CIN];
#pragma unroll
    for (int c = 0; c < CIN; ++c) xv[c] = x[(b * CIN + c) * HW + p];

    float acc[16];
#pragma unroll
    for (int o = 0; o < 16; ++o) acc[o] = 0.f;
#pragma unroll 8
    for (int c = 0; c < CIN; ++c) {
        float xc = xv[c];
#pragma unroll
        for (int o = 0; o < 16; ++o)
            acc[o] += xc * w1[(chunk * 16 + o) * CIN + c];
    }

    unsigned pk[8];
#pragma unroll
    for (int o = 0; o < 16; ++o) {
        acc[o] = gelu_f(acc[o]);
        g_lds[chunk * 16 + o][lane] = acc[o];
    }
#pragma unroll
    for (int d = 0; d < 8; ++d) pk[d] = pack_bf2(acc[2 * d], acc[2 * d + 1]);
    // x1b element offset: ((b*GG+chunk)*HW + p) * 8 dwords
    unsigned* xo = x1b + ((size_t)(b * GG + chunk) * HW + p) * 8;
    *(uint4*)xo       = make_uint4(pk[0], pk[1], pk[2], pk[3]);
    *(uint4*)(xo + 4) = make_uint4(pk[4], pk[5], pk[6], pk[7]);

    __syncthreads();

    float ra[4] = {0.f, 0.f, 0.f, 0.f};
#pragma unroll 8
    for (int c = 0; c < COUT; ++c) {
        float gv = g_lds[c][lane];
#pragma unroll
        for (int jj = 0; jj < 4; ++jj)
            ra[jj] += gv * wr[(chunk * 4 + jj) * COUT + c];
    }
    float4 rv;
    {
        float t[4];
#pragma unroll
        for (int jj = 0; jj < 4; ++jj) {
            int j = chunk * 4 + jj;
            float sc = gr[j] * rsqrtf(vr[j] + 1e-5f);
            float sh = br[j] - mr[j] * sc;
            t[jj] = fmaxf(sc * ra[jj] + sh, 0.f);
        }
        rv = make_float4(t[0], t[1], t[2], t[3]);
    }
    *(float4*)&rbuf[((size_t)b * HW + p) * 16 + chunk * 4] = rv;
}

// K23: per (b,g) block of 256 px. wk[49] in registers (no LDS).
// Taps load 16 interleaved channels as 2x dwordx4. BN1+GELU -> x2b planar bf16.
__global__ __launch_bounds__(256, 4) void k23_involution(
    const unsigned* __restrict__ x1b, const float* __restrict__ rbuf,
    const float* __restrict__ wsp, const float* __restrict__ bsp,
    const float* __restrict__ g1, const float* __restrict__ b1,
    const float* __restrict__ m1, const float* __restrict__ v1,
    bf16* __restrict__ x2b)
{
    int bg = blockIdx.x >> 6;
    int g = bg & 3, b = bg >> 2;
    int p = ((blockIdx.x & 63) << 8) + threadIdx.x;
    int h = p >> 7, w0 = p & 127;

    float r[RED];
    {
        const float4* rp = (const float4*)&rbuf[((size_t)b * HW + p) * 16];
        float4 r0 = rp[0], r1 = rp[1], r2 = rp[2], r3 = rp[3];
        r[0]=r0.x; r[1]=r0.y; r[2]=r0.z; r[3]=r0.w;
        r[4]=r1.x; r[5]=r1.y; r[6]=r1.z; r[7]=r1.w;
        r[8]=r2.x; r[9]=r2.y; r[10]=r2.z; r[11]=r2.w;
        r[12]=r3.x; r[13]=r3.y; r[14]=r3.z; r[15]=r3.w;
    }

    const float* wrow = wsp + g * KKN * RED;
    const float* brow = bsp + g * KKN;
    float wk[KKN];
#pragma unroll 7
    for (int k = 0; k < KKN; ++k) {
        float s = brow[k];
#pragma unroll
        for (int j = 0; j < RED; ++j) s += r[j] * wrow[k * RED + j];
        wk[k] = s;
    }

    const unsigned* xg = x1b + ((size_t)(b * GG + g) * HW) * 8;
    float acc[RED];
#pragma unroll
    for (int c = 0; c < RED; ++c) acc[c] = 0.f;

#pragma unroll
    for (int i = 0; i < 7; ++i) {
        int hh = h + i - 3;                       // wave-uniform
        if ((unsigned)hh < 128u) {
#pragma unroll
            for (int j = 0; j < 7; ++j) {
                int ww = w0 + j - 3;
                if ((unsigned)ww < 128u) {
                    float wv = wk[i * 7 + j];
                    const unsigned* tp = xg + ((size_t)(hh * 128 + ww)) * 8;
                    uint4 A = *(const uint4*)tp;
                    uint4 B = *(const uint4*)(tp + 4);
                    float lo, hi;
                    unpack_bf2(A.x, lo, hi); acc[0] += wv*lo; acc[1] += wv*hi;
                    unpack_bf2(A.y, lo, hi); acc[2] += wv*lo; acc[3] += wv*hi;
                    unpack_bf2(A.z, lo, hi); acc[4] += wv*lo; acc[5] += wv*hi;
                    unpack_bf2(A.w, lo, hi); acc[6] += wv*lo; acc[7] += wv*hi;
                    unpack_bf2(B.x, lo, hi); acc[8] += wv*lo; acc[9] += wv*hi;
                    unpack_bf2(B.y, lo, hi); acc[10]+= wv*lo; acc[11]+= wv*hi;
                    unpack_bf2(B.z, lo, hi); acc[12]+= wv*lo; acc[13]+= wv*hi;
                    unpack_bf2(B.w, lo, hi); acc[14]+= wv*lo; acc[15]+= wv*hi;
                }
            }
        }
    }

#pragma unroll
    for (int c = 0; c < RED; ++c) {
        int ch = g * RED + c;
        float sc = g1[ch] * rsqrtf(v1[ch] + 1e-5f);
        float sh = b1[ch] - m1[ch] * sc;
        x2b[(size_t)(b * COUT + ch) * HW + p] =
            __float2bfloat16(gelu_f(sc * acc[c] + sh));
    }
}

// K4: out = gelu( bn2(conv1x1(x2,w2)) + bnm(conv1x1(x,wm)+bmap) )
// Block = 64 px x 4 chunks, 1 px/thread, s_load weights.
__global__ __launch_bounds__(256, 4) void k4_final(
    const bf16* __restrict__ x2b, const float* __restrict__ x,
    const float* __restrict__ w2, const float* __restrict__ g2,
    const float* __restrict__ b2, const float* __restrict__ m2,
    const float* __restrict__ v2,
    const float* __restrict__ wm, const float* __restrict__ bmap,
    const float* __restrict__ gm, const float* __restrict__ betam,
    const float* __restrict__ mm, const float* __restrict__ vm,
    float* __restrict__ out)
{
    int lane  = threadIdx.x & 63;
    int chunk = __builtin_amdgcn_readfirstlane(threadIdx.x >> 6);
    int b     = blockIdx.x >> 8;
    int p     = ((blockIdx.x & 255) << 6) + lane;

    float acc[16];
#pragma unroll
    for (int o = 0; o < 16; ++o) acc[o] = 0.f;

#pragma unroll 8
    for (int c = 0; c < COUT; ++c) {
        float xc = __bfloat162float(x2b[(size_t)(b * COUT + c) * HW + p]);
#pragma unroll
        for (int o = 0; o < 16; ++o)
            acc[o] += xc * w2[(chunk * 16 + o) * COUT + c];
    }
#pragma unroll
    for (int o = 0; o < 16; ++o) {
        int O = chunk * 16 + o;
        float s2 = g2[O] * rsqrtf(v2[O] + 1e-5f);
        float sm = gm[O] * rsqrtf(vm[O] + 1e-5f);
        acc[o] *= s2 / sm;
    }
#pragma unroll 8
    for (int c = 0; c < CIN; ++c) {
        float xc = x[(b * CIN + c) * HW + p];
#pragma unroll
        for (int o = 0; o < 16; ++o)
            acc[o] += xc * wm[(chunk * 16 + o) * CIN + c];
    }
#pragma unroll
    for (int o = 0; o < 16; ++o) {
        int O = chunk * 16 + o;
        float s2 = g2[O] * rsqrtf(v2[O] + 1e-5f);
        float sm = gm[O] * rsqrtf(vm[O] + 1e-5f);
        float shc = (b2[O] - m2[O] * s2)
                  + (betam[O] + (bmap[O] - mm[O]) * sm);
        out[(size_t)(b * COUT + O) * HW + p] = gelu_f(sm * acc[o] + shc);
    }
}

extern "C" void kernel_launch(void* const* d_in, const int* in_sizes, int n_in,
                              void* d_out, int out_size, void* d_ws, size_t ws_size,
                              hipStream_t stream) {
    const float* x    = (const float*)d_in[0];
    const float* w1   = (const float*)d_in[1];
    const float* wr   = (const float*)d_in[2];
    const float* gr   = (const float*)d_in[3];
    const float* br   = (const float*)d_in[4];
    const float* mr   = (const float*)d_in[5];
    const float* vr   = (const float*)d_in[6];
    const float* wsp  = (const float*)d_in[7];
    const float* bsp  = (const float*)d_in[8];
    const float* g1   = (const float*)d_in[9];
    const float* b1   = (const float*)d_in[10];
    const float* m1   = (const float*)d_in[11];
    const float* v1   = (const float*)d_in[12];
    const float* w2   = (const float*)d_in[13];
    const float* g2   = (const float*)d_in[14];
    const float* b2   = (const float*)d_in[15];
    const float* m2   = (const float*)d_in[16];
    const float* v2   = (const float*)d_in[17];
    const float* wm   = (const float*)d_in[18];
    const float* bmap = (const float*)d_in[19];
    const float* gm   = (const float*)d_in[20];
    const float* betam= (const float*)d_in[21];
    const float* mm   = (const float*)d_in[22];
    const float* vm   = (const float*)d_in[23];

    // workspace:
    //   x1b  bf16 interleaved [b][g][p][c16]  8,388,608 B @ 0
    //   rbuf f32  interleaved [b][p][j16]     4,194,304 B @ 8,388,608
    //   x2b  bf16 planar      [b][ch][p]      8,388,608 B @ 12,582,912
    unsigned* x1b  = (unsigned*)d_ws;
    float*    rbuf = (float*)((char*)d_ws + 8388608);
    bf16*     x2b  = (bf16*)((char*)d_ws + 12582912);

    k1_conv1_gelu_reduce<<<Bsz * HW / 64, 256, 0, stream>>>(
        x, w1, wr, gr, br, mr, vr, x1b, rbuf);
    k23_involution<<<Bsz * GG * HW / 256, 256, 0, stream>>>(
        x1b, rbuf, wsp, bsp, g1, b1, m1, v1, x2b);
    k4_final<<<Bsz * HW / 64, 256, 0, stream>>>(
        x2b, x, w2, g2, b2, m2, v2, wm, bmap, gm, betam, mm, vm,
        (float*)d_out);
}